// Round 13
// baseline (193.314 us; speedup 1.0000x reference)
//
#include <hip/hip_runtime.h>
#include <hip/hip_bf16.h>

// PointProp for MI355X (gfx950) — R17 (= R16 + depth-2 weight prefetch in kD).
//   kA: comp-sum (blocks 0..2047) + U->Wc chain + bias chain + P2/P3/P4 pack
//       (R16 verbatim; at HBM roofline ~92us)
//   kC: P1 packing (R16 verbatim)
//   kD: 32 rows/wave, register B-frags, wave-private act tiles, no barriers,
//       setprio on MFMA clusters (R15 win), NEW: THREE weight buffers
//       (wA/wB/wC, rotation chunk%3, compile-time) -> chunk issued 2 phases
//       (~400cyc) before use, covering L2 latency that depth-1 couldn't.
//       Freed VGPRs for the 3rd buffer by loading csum AT the pass-2 switch
//       (8-reg transient batches; one ~600cyc stall/wave) instead of holding
//       32 cs regs across pass-1. Unified chunk sequence: L1 s=0..15,
//       hidden 16..25, L4 26..35 (frags 0..7 of rotating buffers).
// Session ledger: overlap structures all lose (XCD flags 4x; lockstep fusion
// compresses stream; direct A-frags uncoalesced; stream+latency mix collapses
// vmcnt depth; >256 live VGPR spills). Serial ladder: 187->180 (setprio)
// ->175 (prep fusion)->this.
// Math: out = L4(relu(L3(relu(L2(relu(sig@W0s^T + csum@Wc^T + bias1))))))
// with Wc = W0r@Wu@Wm folded (linearity), H padded 132->160.

typedef float  f32x4  __attribute__((ext_vector_type(4)));
typedef __bf16 bf16x8 __attribute__((ext_vector_type(8)));
typedef unsigned int   u32x2 __attribute__((ext_vector_type(2)));
typedef unsigned short u16x8 __attribute__((ext_vector_type(8)));

__device__ __forceinline__ unsigned short f2bf(float f) {
  unsigned int u = __builtin_bit_cast(unsigned int, f);
  u += 0x7fffu + ((u >> 16) & 1u);   // RNE
  return (unsigned short)(u >> 16);
}

__device__ __forceinline__ u32x2 pack4(f32x4 v) {
  u32x2 r;
  r[0] = (unsigned)f2bf(v[0]) | ((unsigned)f2bf(v[1]) << 16);
  r[1] = (unsigned)f2bf(v[2]) | ((unsigned)f2bf(v[3]) << 16);
  return r;
}

// ---------------- Kernel A: comp-sum + all non-P1 prep (R16 verbatim) -------
__global__ __launch_bounds__(256) void kA(
    const float* __restrict__ comp, const float* __restrict__ W0,
    const float* __restrict__ Wu, const float* __restrict__ Wm,
    const float* __restrict__ bm, const float* __restrict__ bu,
    const float* __restrict__ b0, const float* __restrict__ b1,
    const float* __restrict__ b2, const float* __restrict__ W1,
    const float* __restrict__ W2, const float* __restrict__ W3,
    float* __restrict__ Wc, float* __restrict__ bias1,
    float* __restrict__ b1p, float* __restrict__ b2p,
    unsigned short* __restrict__ csum, unsigned short* __restrict__ P2,
    unsigned short* __restrict__ P3, unsigned short* __restrict__ P4) {
  const int b = blockIdx.x;
  const int d = threadIdx.x;
  if (b < 2048) {
    const f32x4* cp = (const f32x4*)comp;
    const size_t base = (size_t)b * 2048 + d;     // f32x4 units
    f32x4 a[8];
#pragma unroll
    for (int j = 0; j < 8; ++j) a[j] = cp[base + j * 256];
#pragma unroll
    for (int k = 1; k < 8; ++k) {
      f32x4 t0[8];
#pragma unroll
      for (int j = 0; j < 8; ++j)
        t0[j] = cp[base + (size_t)k * 4194304u + j * 256];
#pragma unroll
      for (int j = 0; j < 8; ++j) a[j] += t0[j];
    }
    u32x2* op = (u32x2*)csum;
#pragma unroll
    for (int j = 0; j < 8; ++j) op[base + j * 256] = pack4(a[j]);
  } else if (b < 2180) {
    __shared__ float u[256];
    const int h = b - 2048;
    float s = 0.f;
#pragma unroll 8
    for (int i = 0; i < 256; ++i) s += W0[h * 512 + 256 + i] * Wu[i * 256 + d];
    u[d] = s;
    __syncthreads();
    float s2 = 0.f;
#pragma unroll 8
    for (int j = 0; j < 256; ++j) s2 += u[j] * Wm[j * 256 + d];
    Wc[h * 256 + d] = s2;
  } else if (b == 2180) {
    __shared__ float bml[256];
    __shared__ float rbl[256];
    bml[d] = bm[d];
    __syncthreads();
    {
      const f32x4* wr = (const f32x4*)(Wu + d * 256);
      const f32x4* bm4 = (const f32x4*)bml;
      float s = 0.f;
#pragma unroll 8
      for (int i = 0; i < 64; ++i) {
        f32x4 w = wr[i], v = bm4[i];
        s += w[0] * v[0] + w[1] * v[1] + w[2] * v[2] + w[3] * v[3];
      }
      rbl[d] = 8.f * s + bu[d];
    }
    __syncthreads();
    if (d < 160) {
      float v = 0.f;
      if (d < 132) {
        float s = 0.f;
#pragma unroll 8
        for (int j = 0; j < 256; ++j) s += W0[d * 512 + 256 + j] * rbl[j];
        v = b0[d] + s;
      }
      bias1[d] = v;
      b1p[d] = (d < 132) ? b1[d] : 0.f;
      b2p[d] = (d < 132) ? b2[d] : 0.f;
    }
  } else {
    const int e2 = (b - 2181) * 256 + d;          // 0..92159
    unsigned short* dst; int NT, rel, mode;
    if (e2 < 25600)      { dst = P2; NT = 10; rel = e2;          mode = 1; }
    else if (e2 < 51200) { dst = P3; NT = 10; rel = e2 - 25600;  mode = 2; }
    else                 { dst = P4; NT = 16; rel = e2 - 51200;  mode = 3; }
    int chunk = rel >> 9, q = rel & 511;
    int lane = q >> 3, j = q & 7;
    int kk = chunk / NT, nt = chunk - kk * NT;
    int k = kk * 32 + (lane >> 4) * 8 + j;
    int n = nt * 16 + (lane & 15);
    float v = 0.f;
    if (mode == 1) {
      if (n < 132 && k < 132) v = W1[n * 132 + k];
    } else if (mode == 2) {
      if (n < 132 && k < 132) v = W2[n * 132 + k];
    } else {
      if (k < 132) v = W3[n * 132 + k];
    }
    dst[rel] = f2bf(v);
  }
}

// ---------------- Kernel C: pack P1 (needs Wc) — R16 verbatim ---------------
__global__ __launch_bounds__(256) void kC(
    const float* __restrict__ W0, const float* __restrict__ Wc,
    unsigned short* __restrict__ P1) {
  int e = blockIdx.x * 256 + threadIdx.x;        // 0..81919
  int chunk = e >> 9, q = e & 511;
  int lane = q >> 3, j = q & 7;
  int kk = chunk / 10, nt = chunk - kk * 10;
  int k = kk * 32 + (lane >> 4) * 8 + j;
  int n = nt * 16 + (lane & 15);
  float v = 0.f;
  if (n < 132) v = (k < 256) ? W0[n * 512 + k] : Wc[n * 256 + (k - 256)];
  P1[e] = f2bf(v);
}

// ---- weight issue macros (direct L2/L1 -> VGPR, coalesced 1KB per frag) ----
// chunks 0..25 contiguous at c*10240; L4 group q (q=0..9) 8-frag at
// 266240 + (q%5)*16384 + (q/5)*8192.
#define WISS(BUF, CHUNK)                                                     \
  {                                                                          \
    _Pragma("unroll") for (int nt = 0; nt < 10; ++nt)                        \
        BUF[nt] = *(const bf16x8*)(Pb + (CHUNK) * 10240 + nt * 1024 +        \
                                   lane * 16);                               \
  }
#define WISSL4(BUF, Q)                                                       \
  {                                                                          \
    _Pragma("unroll") for (int nt = 0; nt < 8; ++nt)                         \
        BUF[nt] = *(const bf16x8*)(Pb + 266240 + ((Q) % 5) * 16384 +         \
                                   ((Q) / 5) * 8192 + nt * 1024 + lane * 16);\
  }
// rotation helpers: issue/consume by compile-time index%3
#define WPRE(IDX, CHUNK)                                                     \
  {                                                                          \
    if (((IDX) % 3) == 0) { WISS(wA, CHUNK); }                               \
    else if (((IDX) % 3) == 1) { WISS(wB, CHUNK); }                          \
    else { WISS(wC, CHUNK); }                                                \
  }
#define WPREL4(IDX, Q)                                                       \
  {                                                                          \
    if (((IDX) % 3) == 0) { WISSL4(wA, Q); }                                 \
    else if (((IDX) % 3) == 1) { WISSL4(wB, Q); }                            \
    else { WISSL4(wC, Q); }                                                  \
  }
#define MFMA10(ACC, BUF, AF)                                                 \
  {                                                                          \
    _Pragma("unroll") for (int nt = 0; nt < 10; ++nt)                        \
        ACC[nt] = __builtin_amdgcn_mfma_f32_16x16x32_bf16(AF, BUF[nt],       \
                                                          ACC[nt], 0, 0, 0); \
  }
#define MFMA10X2(IDX, AF0, AF1)                                              \
  {                                                                          \
    __builtin_amdgcn_s_setprio(1);                                           \
    if (((IDX) % 3) == 0) { MFMA10(acc0, wA, AF0); MFMA10(acc1, wA, AF1); }  \
    else if (((IDX) % 3) == 1) { MFMA10(acc0, wB, AF0);                      \
                                 MFMA10(acc1, wB, AF1); }                    \
    else { MFMA10(acc0, wC, AF0); MFMA10(acc1, wC, AF1); }                   \
    __builtin_amdgcn_s_setprio(0);                                           \
  }

// ---------------- Kernel D: 4-layer MLP, depth-2 weight prefetch ------------
// grid 512 x 256; wave owns 32 rows as two 16-row groups (act0/act1, 8KB
// each, wave-private, XOR-swizzled). Buffers wA/wB/wC rotate by chunk%3;
// chunk c issued at sequence step c-2 (2-phase lead ~400cyc covers L2).
__global__ __launch_bounds__(256, 2) void kD(
    const float* __restrict__ signal, const unsigned short* __restrict__ csum,
    const unsigned short* __restrict__ Pseq,
    const float* __restrict__ bias1, const float* __restrict__ b1p,
    const float* __restrict__ b2p, const float* __restrict__ b3,
    float* __restrict__ out) {
  extern __shared__ char lds[];
  const int tid = threadIdx.x;
  const int wave = tid >> 6;
  const int lane = tid & 63;
  const int lhalf = lane >> 4;
  const int l16 = lane & 15;
  const int r2 = lane >> 5, c32 = lane & 31;
  char* act0 = lds + wave * 16384;
  char* act1 = act0 + 8192;
  const char* Pb = (const char*)Pseq;
  const int row0 = ((int)blockIdx.x * 4 + wave) * 32;
  const int asw = (l16 & 7) << 4;
  const f32x4* sp = (const f32x4*)signal;

  bf16x8 wA[10], wB[10], wC[10];
  WISS(wA, 0);                       // chunk 0 (longest lead)

  // ---- prologue: signal -> act tiles (one group at a time: caps VGPRs) ----
  {
    f32x4 sg[16];
#pragma unroll
    for (int r = 0; r < 16; ++r) sg[r] = sp[(size_t)(row0 + r) * 64 + lane];
#pragma unroll
    for (int r = 0; r < 16; ++r)
      *(u32x2*)(act0 + r * 512 + ((lane * 8) ^ ((r & 7) << 4))) = pack4(sg[r]);
  }
  {
    f32x4 sg[16];
#pragma unroll
    for (int r = 0; r < 16; ++r)
      sg[r] = sp[(size_t)(row0 + 16 + r) * 64 + lane];
#pragma unroll
    for (int r = 0; r < 16; ++r)
      *(u32x2*)(act1 + r * 512 + ((lane * 8) ^ ((r & 7) << 4))) = pack4(sg[r]);
  }
  WISS(wB, 1);                       // chunk 1

  f32x4 acc0[10], acc1[10];
#pragma unroll
  for (int i = 0; i < 10; ++i) {
    acc0[i] = f32x4{0.f, 0.f, 0.f, 0.f};
    acc1[i] = f32x4{0.f, 0.f, 0.f, 0.f};
  }

  // ---- L1: sequence s=0..15 (pass1 sig chunks 0..7, pass2 csum 8..15) ----
#pragma unroll
  for (int s = 0; s < 16; ++s) {
    WPRE(s + 2, s + 2);              // chunks 2..17 (16,17 are hidden chunks)
    if (s == 8) {
      // ---- pass-2 switch: load csum NOW (regs freed during pass-1),
      //      8-reg transient batches, write swizzled into act tiles ----
      asm volatile("" ::: "memory");
#pragma unroll
      for (int half = 0; half < 2; ++half) {
        char* at = half ? act1 : act0;
        const int rbase = row0 + half * 16;
#pragma unroll
        for (int g = 0; g < 2; ++g) {          // row-pairs {0..3}, {4..7}
          u16x8 t0 = *(const u16x8*)(csum +
              (size_t)(rbase + 2 * (4 * g + 0) + r2) * 256 + c32 * 8);
          u16x8 t1 = *(const u16x8*)(csum +
              (size_t)(rbase + 2 * (4 * g + 1) + r2) * 256 + c32 * 8);
          u16x8 t2 = *(const u16x8*)(csum +
              (size_t)(rbase + 2 * (4 * g + 2) + r2) * 256 + c32 * 8);
          u16x8 t3 = *(const u16x8*)(csum +
              (size_t)(rbase + 2 * (4 * g + 3) + r2) * 256 + c32 * 8);
          const int rw0 = 2 * (4 * g + 0) + r2;
          const int rw1 = 2 * (4 * g + 1) + r2;
          const int rw2 = 2 * (4 * g + 2) + r2;
          const int rw3 = 2 * (4 * g + 3) + r2;
          *(u16x8*)(at + rw0 * 512 + ((c32 * 16) ^ ((rw0 & 7) << 4))) = t0;
          *(u16x8*)(at + rw1 * 512 + ((c32 * 16) ^ ((rw1 & 7) << 4))) = t1;
          *(u16x8*)(at + rw2 * 512 + ((c32 * 16) ^ ((rw2 & 7) << 4))) = t2;
          *(u16x8*)(at + rw3 * 512 + ((c32 * 16) ^ ((rw3 & 7) << 4))) = t3;
        }
      }
      asm volatile("" ::: "memory");
    }
    const int col = (s < 8) ? (s * 64) : ((s - 8) * 64);
    bf16x8 af0 =
        *(const bf16x8*)(act0 + l16 * 512 + ((col + lhalf * 16) ^ asw));
    bf16x8 af1 =
        *(const bf16x8*)(act1 + l16 * 512 + ((col + lhalf * 16) ^ asw));
    MFMA10X2(s, af0, af1);
  }

  // bias + relu -> act tiles
  {
    float bv[10];
#pragma unroll
    for (int nt = 0; nt < 10; ++nt) bv[nt] = bias1[nt * 16 + l16];
    asm volatile("" ::: "memory");
#pragma unroll
    for (int nt = 0; nt < 10; ++nt) {
#pragma unroll
      for (int r = 0; r < 4; ++r) {
        const int row = lhalf * 4 + r;
        const int off = (((nt * 16 + l16) * 2) ^ ((row & 7) << 4));
        float v0 = fmaxf(acc0[nt][r] + bv[nt], 0.f);
        float v1 = fmaxf(acc1[nt][r] + bv[nt], 0.f);
        *(unsigned short*)(act0 + row * 512 + off) = f2bf(v0);
        *(unsigned short*)(act1 + row * 512 + off) = f2bf(v1);
      }
    }
    asm volatile("" ::: "memory");
  }

  // ---- hidden layers: chunks 16..20 (W1), 21..25 (W2) ----
#pragma unroll
  for (int L = 0; L < 2; ++L) {
    const float* hbias = L ? b2p : b1p;
#pragma unroll
    for (int i = 0; i < 10; ++i) {
      acc0[i] = f32x4{0.f, 0.f, 0.f, 0.f};
      acc1[i] = f32x4{0.f, 0.f, 0.f, 0.f};
    }
#pragma unroll
    for (int qq = 0; qq < 5; ++qq) {
      const int cc = 16 + L * 5 + qq;
      // prefetch cc+2: chunk if <=25, else L4 group (cc+2-26)
      if (cc + 2 <= 25) { WPRE(cc + 2, cc + 2); }
      else              { WPREL4(cc + 2, cc + 2 - 26); }
      bf16x8 af0 =
          *(const bf16x8*)(act0 + l16 * 512 + ((qq * 64 + lhalf * 16) ^ asw));
      bf16x8 af1 =
          *(const bf16x8*)(act1 + l16 * 512 + ((qq * 64 + lhalf * 16) ^ asw));
      MFMA10X2(cc, af0, af1);
    }
    float bv[10];
#pragma unroll
    for (int nt = 0; nt < 10; ++nt) bv[nt] = hbias[nt * 16 + l16];
    asm volatile("" ::: "memory");
#pragma unroll
    for (int nt = 0; nt < 10; ++nt) {
#pragma unroll
      for (int r = 0; r < 4; ++r) {
        const int row = lhalf * 4 + r;
        const int off = (((nt * 16 + l16) * 2) ^ ((row & 7) << 4));
        float v0 = fmaxf(acc0[nt][r] + bv[nt], 0.f);
        float v1 = fmaxf(acc1[nt][r] + bv[nt], 0.f);
        *(unsigned short*)(act0 + row * 512 + off) = f2bf(v0);
        *(unsigned short*)(act1 + row * 512 + off) = f2bf(v1);
      }
    }
    asm volatile("" ::: "memory");
  }

  // ---- layer 4: halves h=0,1; seq index sq=26+q, q=h*5+kk ----
#pragma unroll
  for (int h = 0; h < 2; ++h) {
    f32x4 a40[8], a41[8];
#pragma unroll
    for (int i = 0; i < 8; ++i) {
      a40[i] = f32x4{0.f, 0.f, 0.f, 0.f};
      a41[i] = f32x4{0.f, 0.f, 0.f, 0.f};
    }
#pragma unroll
    for (int kk = 0; kk < 5; ++kk) {
      const int q = h * 5 + kk;
      const int sq = 26 + q;
      if (q + 2 <= 9) { WPREL4(sq + 2, q + 2); }
      bf16x8 af0 =
          *(const bf16x8*)(act0 + l16 * 512 + ((kk * 64 + lhalf * 16) ^ asw));
      bf16x8 af1 =
          *(const bf16x8*)(act1 + l16 * 512 + ((kk * 64 + lhalf * 16) ^ asw));
      __builtin_amdgcn_s_setprio(1);
#pragma unroll
      for (int i = 0; i < 8; ++i) {
        if ((sq % 3) == 0) {
          a40[i] = __builtin_amdgcn_mfma_f32_16x16x32_bf16(af0, wA[i], a40[i],
                                                           0, 0, 0);
          a41[i] = __builtin_amdgcn_mfma_f32_16x16x32_bf16(af1, wA[i], a41[i],
                                                           0, 0, 0);
        } else if ((sq % 3) == 1) {
          a40[i] = __builtin_amdgcn_mfma_f32_16x16x32_bf16(af0, wB[i], a40[i],
                                                           0, 0, 0);
          a41[i] = __builtin_amdgcn_mfma_f32_16x16x32_bf16(af1, wB[i], a41[i],
                                                           0, 0, 0);
        } else {
          a40[i] = __builtin_amdgcn_mfma_f32_16x16x32_bf16(af0, wC[i], a40[i],
                                                           0, 0, 0);
          a41[i] = __builtin_amdgcn_mfma_f32_16x16x32_bf16(af1, wC[i], a41[i],
                                                           0, 0, 0);
        }
      }
      __builtin_amdgcn_s_setprio(0);
    }
    // store this half for both groups
    float bv[8];
#pragma unroll
    for (int i = 0; i < 8; ++i) bv[i] = b3[(h * 8 + i) * 16 + l16];
    float* op0 = out + (size_t)(row0 + lhalf * 4) * 256 + h * 128 + l16;
    float* op1 = out + (size_t)(row0 + 16 + lhalf * 4) * 256 + h * 128 + l16;
#pragma unroll
    for (int i = 0; i < 8; ++i) {
#pragma unroll
      for (int r = 0; r < 4; ++r) {
        op0[(size_t)r * 256 + i * 16] = a40[i][r] + bv[i];
        op1[(size_t)r * 256 + i * 16] = a41[i][r] + bv[i];
      }
    }
  }
}

// ---------------- launcher ----------------
extern "C" void kernel_launch(void* const* d_in, const int* in_sizes, int n_in,
                              void* d_out, int out_size, void* d_ws, size_t ws_size,
                              hipStream_t stream) {
  const float* signal = (const float*)d_in[0];
  const float* comp   = (const float*)d_in[1];
  const float* Wm = (const float*)d_in[2];
  const float* bm = (const float*)d_in[3];
  const float* Wu = (const float*)d_in[4];
  const float* bu = (const float*)d_in[5];
  const float* W0 = (const float*)d_in[6];
  const float* b0 = (const float*)d_in[7];
  const float* W1 = (const float*)d_in[8];
  const float* b1 = (const float*)d_in[9];
  const float* W2 = (const float*)d_in[10];
  const float* b2 = (const float*)d_in[11];
  const float* W3 = (const float*)d_in[12];
  const float* b3 = (const float*)d_in[13];

  char* ws = (char*)d_ws;
  float* Wc    = (float*)(ws + 0);        // 33792 f32 (135168 B)
  float* bias1 = (float*)(ws + 135168);   // 160 f32
  float* b1p   = (float*)(ws + 135808);   // 160 f32
  float* b2p   = (float*)(ws + 136448);   // 160 f32
  // contiguous packed-weight sequence (chunk offsets off P1):
  unsigned short* P1 = (unsigned short*)(ws + 137216);  // 81920 u16 (160KB)
  unsigned short* P2 = (unsigned short*)(ws + 301056);  // 25600 u16 (50KB)
  unsigned short* P3 = (unsigned short*)(ws + 352256);  // 25600 u16 (50KB)
  unsigned short* P4 = (unsigned short*)(ws + 403456);  // 40960 u16 (80KB)
  unsigned short* csum = (unsigned short*)(ws + 485376); // [N,256] bf16 33.5MB

  hipLaunchKernelGGL(kA, dim3(2541), dim3(256), 0, stream,
                     comp, W0, Wu, Wm, bm, bu, b0, b1, b2, W1, W2, W3,
                     Wc, bias1, b1p, b2p, csum, P2, P3, P4);
  hipLaunchKernelGGL(kC, dim3(320), dim3(256), 0, stream, W0, Wc, P1);
  hipLaunchKernelGGL(kD, dim3(512), dim3(256), 65536, stream,
                     signal, csum, P1, bias1, b1p, b2p, b3, (float*)d_out);
}

// Round 14
// 175.500 us; speedup vs baseline: 1.1015x; 1.1015x over previous
//
#include <hip/hip_runtime.h>
#include <hip/hip_bf16.h>

// PointProp for MI355X (gfx950) — R18 (= R16, the verified best at 175.0us).
//   kA: comp-sum (blocks 0..2047, streams first) + U->Wc per-block LDS chain
//       (blocks 2048..2179) + rb/bias1/b1p/b2p single block (2180) +
//       P2/P3/P4 packing (2181..2540, no deps).
//   kC: P1 packing only (needs Wc) — 320 blocks.
//   kD: 32 rows/wave, register B-frags shared by two 16-row groups,
//       wave-private act tiles, no barriers, s_setprio(1) around MFMA
//       clusters (verified -6.6us), depth-1 weight prefetch (depth-2 with a
//       3rd buffer REGRESSED +18us in R17 — register-pressure wall).
// Final ledger: serial ladder 190.7 (R4) -> 187.2 (R10 reg-weights) ->
// 180.3 (R15 setprio) -> 175.0 (R16 prep fusion). Regressions: occupancy
// trade (R12 +13), depth-2 prefetch (R17 +18), all overlap structures
// (R5-R9/R11/R13: XCD-non-coherent flags; lockstep stream compression;
// uncoalesced A-frags; vmcnt stream-collapse; >256-VGPR spills).
// kA is at the HBM roofline (~92us for 570MB). kD ~81us vs ~46us floor —
// latency-structural, both available levers tested and regressed.
// Math: out = L4(relu(L3(relu(L2(relu(sig@W0s^T + csum@Wc^T + bias1))))))
// with Wc = W0r@Wu@Wm folded (linearity), H padded 132->160.

typedef float  f32x4  __attribute__((ext_vector_type(4)));
typedef __bf16 bf16x8 __attribute__((ext_vector_type(8)));
typedef unsigned int   u32x2 __attribute__((ext_vector_type(2)));
typedef unsigned short u16x8 __attribute__((ext_vector_type(8)));

__device__ __forceinline__ unsigned short f2bf(float f) {
  unsigned int u = __builtin_bit_cast(unsigned int, f);
  u += 0x7fffu + ((u >> 16) & 1u);   // RNE
  return (unsigned short)(u >> 16);
}

__device__ __forceinline__ u32x2 pack4(f32x4 v) {
  u32x2 r;
  r[0] = (unsigned)f2bf(v[0]) | ((unsigned)f2bf(v[1]) << 16);
  r[1] = (unsigned)f2bf(v[2]) | ((unsigned)f2bf(v[3]) << 16);
  return r;
}

// ---------------- Kernel A: comp-sum + all non-P1 prep ----------------------
// blocks 0..2047: comp-sum rows [b*32, b*32+32), k-serial (pure HBM stream)
// blocks 2048..2179: h=b-2048: U row h (LDS) -> Wc row h
// block 2180: rb = 8*(Wu@bm)+bu; bias1 = b0 + W0r@rb; b1p/b2p
// blocks 2181..2540: pack P2/P3/P4 (W1/W2/W3 only — independent)
__global__ __launch_bounds__(256) void kA(
    const float* __restrict__ comp, const float* __restrict__ W0,
    const float* __restrict__ Wu, const float* __restrict__ Wm,
    const float* __restrict__ bm, const float* __restrict__ bu,
    const float* __restrict__ b0, const float* __restrict__ b1,
    const float* __restrict__ b2, const float* __restrict__ W1,
    const float* __restrict__ W2, const float* __restrict__ W3,
    float* __restrict__ Wc, float* __restrict__ bias1,
    float* __restrict__ b1p, float* __restrict__ b2p,
    unsigned short* __restrict__ csum, unsigned short* __restrict__ P2,
    unsigned short* __restrict__ P3, unsigned short* __restrict__ P4) {
  const int b = blockIdx.x;
  const int d = threadIdx.x;
  if (b < 2048) {
    // ---- comp-sum (k-serial; cb = b) ----
    const f32x4* cp = (const f32x4*)comp;
    const size_t base = (size_t)b * 2048 + d;     // f32x4 units
    f32x4 a[8];
#pragma unroll
    for (int j = 0; j < 8; ++j) a[j] = cp[base + j * 256];
#pragma unroll
    for (int k = 1; k < 8; ++k) {
      f32x4 t0[8];
#pragma unroll
      for (int j = 0; j < 8; ++j)
        t0[j] = cp[base + (size_t)k * 4194304u + j * 256];
#pragma unroll
      for (int j = 0; j < 8; ++j) a[j] += t0[j];
    }
    u32x2* op = (u32x2*)csum;
#pragma unroll
    for (int j = 0; j < 8; ++j) op[base + j * 256] = pack4(a[j]);
  } else if (b < 2180) {
    // ---- U row -> Wc row, chained through LDS ----
    __shared__ float u[256];
    const int h = b - 2048;
    float s = 0.f;
#pragma unroll 8
    for (int i = 0; i < 256; ++i) s += W0[h * 512 + 256 + i] * Wu[i * 256 + d];
    u[d] = s;
    __syncthreads();
    float s2 = 0.f;
#pragma unroll 8
    for (int j = 0; j < 256; ++j) s2 += u[j] * Wm[j * 256 + d];
    Wc[h * 256 + d] = s2;
  } else if (b == 2180) {
    // ---- rb + bias1 + padded biases ----
    __shared__ float bml[256];
    __shared__ float rbl[256];
    bml[d] = bm[d];
    __syncthreads();
    {
      const f32x4* wr = (const f32x4*)(Wu + d * 256);
      const f32x4* bm4 = (const f32x4*)bml;
      float s = 0.f;
#pragma unroll 8
      for (int i = 0; i < 64; ++i) {
        f32x4 w = wr[i], v = bm4[i];
        s += w[0] * v[0] + w[1] * v[1] + w[2] * v[2] + w[3] * v[3];
      }
      rbl[d] = 8.f * s + bu[d];
    }
    __syncthreads();
    if (d < 160) {
      float v = 0.f;
      if (d < 132) {
        float s = 0.f;
#pragma unroll 8
        for (int j = 0; j < 256; ++j) s += W0[d * 512 + 256 + j] * rbl[j];
        v = b0[d] + s;
      }
      bias1[d] = v;
      b1p[d] = (d < 132) ? b1[d] : 0.f;
      b2p[d] = (d < 132) ? b2[d] : 0.f;
    }
  } else {
    // ---- pack P2/P3/P4 (e2 = original e - 81920) ----
    const int e2 = (b - 2181) * 256 + d;          // 0..92159
    unsigned short* dst; int NT, rel, mode;
    if (e2 < 25600)      { dst = P2; NT = 10; rel = e2;          mode = 1; }
    else if (e2 < 51200) { dst = P3; NT = 10; rel = e2 - 25600;  mode = 2; }
    else                 { dst = P4; NT = 16; rel = e2 - 51200;  mode = 3; }
    int chunk = rel >> 9, q = rel & 511;
    int lane = q >> 3, j = q & 7;
    int kk = chunk / NT, nt = chunk - kk * NT;
    int k = kk * 32 + (lane >> 4) * 8 + j;
    int n = nt * 16 + (lane & 15);
    float v = 0.f;
    if (mode == 1) {
      if (n < 132 && k < 132) v = W1[n * 132 + k];
    } else if (mode == 2) {
      if (n < 132 && k < 132) v = W2[n * 132 + k];
    } else {
      if (k < 132) v = W3[n * 132 + k];
    }
    dst[rel] = f2bf(v);
  }
}

// ---------------- Kernel C: pack P1 (needs Wc) ------------------------------
// Chunk (kk,nt) = 1024B: lane l holds B[kk*32+(l>>4)*8+j][nt*16+(l&15)], j=0..7.
// L1: K=512, N=160 -> 81920 elems, 320 blocks.
__global__ __launch_bounds__(256) void kC(
    const float* __restrict__ W0, const float* __restrict__ Wc,
    unsigned short* __restrict__ P1) {
  int e = blockIdx.x * 256 + threadIdx.x;        // 0..81919
  int chunk = e >> 9, q = e & 511;
  int lane = q >> 3, j = q & 7;
  int kk = chunk / 10, nt = chunk - kk * 10;
  int k = kk * 32 + (lane >> 4) * 8 + j;
  int n = nt * 16 + (lane & 15);
  float v = 0.f;
  if (n < 132) v = (k < 256) ? W0[n * 512 + k] : Wc[n * 256 + (k - 256)];
  P1[e] = f2bf(v);
}

// ---- per-wave weight issue (direct L2/L1 -> VGPR, coalesced 1KB per frag) --
// chunks 0..25 contiguous at c*10240; L4 chunk (h,kk) 8-frag group at
// 266240 + kk*16384 + h*8192.
#define WISS(BUF, CHUNK)                                                     \
  {                                                                          \
    _Pragma("unroll") for (int nt = 0; nt < 10; ++nt)                        \
        BUF[nt] = *(const bf16x8*)(Pb + (CHUNK) * 10240 + nt * 1024 +        \
                                   lane * 16);                               \
  }
#define WISS8L4(BUF, Q)                                                      \
  {                                                                          \
    _Pragma("unroll") for (int nt = 0; nt < 8; ++nt)                         \
        BUF[nt] = *(const bf16x8*)(Pb + 266240 + ((Q) % 5) * 16384 +         \
                                   ((Q) / 5) * 8192 + nt * 1024 + lane * 16);\
  }
#define MFMA10(ACC, BUF, AF)                                                 \
  {                                                                          \
    _Pragma("unroll") for (int nt = 0; nt < 10; ++nt)                        \
        ACC[nt] = __builtin_amdgcn_mfma_f32_16x16x32_bf16(AF, BUF[nt],       \
                                                          ACC[nt], 0, 0, 0); \
  }

// ---------------- Kernel D: 4-layer MLP (setprio win, depth-1 prefetch) -----
__global__ __launch_bounds__(256, 2) void kD(
    const float* __restrict__ signal, const unsigned short* __restrict__ csum,
    const unsigned short* __restrict__ Pseq,
    const float* __restrict__ bias1, const float* __restrict__ b1p,
    const float* __restrict__ b2p, const float* __restrict__ b3,
    float* __restrict__ out) {
  extern __shared__ char lds[];
  const int tid = threadIdx.x;
  const int wave = tid >> 6;
  const int lane = tid & 63;
  const int lhalf = lane >> 4;
  const int l16 = lane & 15;
  const int r2 = lane >> 5, c32 = lane & 31;
  char* act0 = lds + wave * 16384;
  char* act1 = act0 + 8192;
  const char* Pb = (const char*)Pseq;
  const int row0 = ((int)blockIdx.x * 4 + wave) * 32;
  const int asw = (l16 & 7) << 4;
  const f32x4* sp = (const f32x4*)signal;

  // ---- prologue: signal -> act tiles (one group at a time: caps VGPRs) ----
  {
    f32x4 sg[16];
#pragma unroll
    for (int r = 0; r < 16; ++r) sg[r] = sp[(size_t)(row0 + r) * 64 + lane];
#pragma unroll
    for (int r = 0; r < 16; ++r)
      *(u32x2*)(act0 + r * 512 + ((lane * 8) ^ ((r & 7) << 4))) = pack4(sg[r]);
  }
  {
    f32x4 sg[16];
#pragma unroll
    for (int r = 0; r < 16; ++r)
      sg[r] = sp[(size_t)(row0 + 16 + r) * 64 + lane];
#pragma unroll
    for (int r = 0; r < 16; ++r)
      *(u32x2*)(act1 + r * 512 + ((lane * 8) ^ ((r & 7) << 4))) = pack4(sg[r]);
  }

  // csum for both groups (issued early; consumed at pass-2 switch)
  u16x8 cs0[8], cs1[8];
#pragma unroll
  for (int j = 0; j < 8; ++j)
    cs0[j] = *(const u16x8*)(csum + (size_t)(row0 + 2 * j + r2) * 256 + c32 * 8);
#pragma unroll
  for (int j = 0; j < 8; ++j)
    cs1[j] =
        *(const u16x8*)(csum + (size_t)(row0 + 16 + 2 * j + r2) * 256 + c32 * 8);

  bf16x8 wA[10], wB[10];
  WISS(wA, 0);

  f32x4 acc0[10], acc1[10];
#pragma unroll
  for (int i = 0; i < 10; ++i) {
    acc0[i] = f32x4{0.f, 0.f, 0.f, 0.f};
    acc1[i] = f32x4{0.f, 0.f, 0.f, 0.f};
  }

  // ---- L1 pass 1 (signal half), chunks 0..7 ----
#pragma unroll
  for (int kk = 0; kk < 8; ++kk) {
    if ((kk + 1) & 1) { WISS(wB, kk + 1); } else { WISS(wA, kk + 1); }
    bf16x8 af0 =
        *(const bf16x8*)(act0 + l16 * 512 + ((kk * 64 + lhalf * 16) ^ asw));
    bf16x8 af1 =
        *(const bf16x8*)(act1 + l16 * 512 + ((kk * 64 + lhalf * 16) ^ asw));
    __builtin_amdgcn_s_setprio(1);
    if (kk & 1) {
      MFMA10(acc0, wB, af0); MFMA10(acc1, wB, af1);
    } else {
      MFMA10(acc0, wA, af0); MFMA10(acc1, wA, af1);
    }
    __builtin_amdgcn_s_setprio(0);
  }

  // overwrite act tiles with comp-sum (wave-local)
  asm volatile("" ::: "memory");
#pragma unroll
  for (int j = 0; j < 8; ++j) {
    const int rw = 2 * j + r2;
    *(u16x8*)(act0 + rw * 512 + ((c32 * 16) ^ ((rw & 7) << 4))) = cs0[j];
    *(u16x8*)(act1 + rw * 512 + ((c32 * 16) ^ ((rw & 7) << 4))) = cs1[j];
  }
  asm volatile("" ::: "memory");

  // ---- L1 pass 2 (comp-sum half), chunks 8..15 ----
#pragma unroll
  for (int kk = 8; kk < 16; ++kk) {
    if ((kk + 1) & 1) { WISS(wB, kk + 1); } else { WISS(wA, kk + 1); }
    bf16x8 af0 = *(const bf16x8*)(act0 + l16 * 512 +
                                  (((kk - 8) * 64 + lhalf * 16) ^ asw));
    bf16x8 af1 = *(const bf16x8*)(act1 + l16 * 512 +
                                  (((kk - 8) * 64 + lhalf * 16) ^ asw));
    __builtin_amdgcn_s_setprio(1);
    if (kk & 1) {
      MFMA10(acc0, wB, af0); MFMA10(acc1, wB, af1);
    } else {
      MFMA10(acc0, wA, af0); MFMA10(acc1, wA, af1);
    }
    __builtin_amdgcn_s_setprio(0);
  }

  // bias + relu -> act tiles
  {
    float bv[10];
#pragma unroll
    for (int nt = 0; nt < 10; ++nt) bv[nt] = bias1[nt * 16 + l16];
    asm volatile("" ::: "memory");
#pragma unroll
    for (int nt = 0; nt < 10; ++nt) {
#pragma unroll
      for (int r = 0; r < 4; ++r) {
        const int row = lhalf * 4 + r;
        const int off = (((nt * 16 + l16) * 2) ^ ((row & 7) << 4));
        float v0 = fmaxf(acc0[nt][r] + bv[nt], 0.f);
        float v1 = fmaxf(acc1[nt][r] + bv[nt], 0.f);
        *(unsigned short*)(act0 + row * 512 + off) = f2bf(v0);
        *(unsigned short*)(act1 + row * 512 + off) = f2bf(v1);
      }
    }
    asm volatile("" ::: "memory");
  }

  // ---- hidden layers: chunks 16..20 (W1), 21..25 (W2) ----
  bf16x8 w4A[8], w4B[8];
#pragma unroll
  for (int L = 0; L < 2; ++L) {
    const float* hbias = L ? b2p : b1p;
#pragma unroll
    for (int i = 0; i < 10; ++i) {
      acc0[i] = f32x4{0.f, 0.f, 0.f, 0.f};
      acc1[i] = f32x4{0.f, 0.f, 0.f, 0.f};
    }
#pragma unroll
    for (int qq = 0; qq < 5; ++qq) {
      const int cc = 16 + L * 5 + qq;      // chunk in use (even->wA, odd->wB)
      if (cc < 25) {
        if (cc & 1) { WISS(wA, cc + 1); } else { WISS(wB, cc + 1); }
      } else {
        WISS8L4(w4A, 0);                   // prefetch L4 q=0
      }
      bf16x8 af0 =
          *(const bf16x8*)(act0 + l16 * 512 + ((qq * 64 + lhalf * 16) ^ asw));
      bf16x8 af1 =
          *(const bf16x8*)(act1 + l16 * 512 + ((qq * 64 + lhalf * 16) ^ asw));
      __builtin_amdgcn_s_setprio(1);
      if (cc & 1) {
        MFMA10(acc0, wB, af0); MFMA10(acc1, wB, af1);
      } else {
        MFMA10(acc0, wA, af0); MFMA10(acc1, wA, af1);
      }
      __builtin_amdgcn_s_setprio(0);
    }
    float bv[10];
#pragma unroll
    for (int nt = 0; nt < 10; ++nt) bv[nt] = hbias[nt * 16 + l16];
    asm volatile("" ::: "memory");
#pragma unroll
    for (int nt = 0; nt < 10; ++nt) {
#pragma unroll
      for (int r = 0; r < 4; ++r) {
        const int row = lhalf * 4 + r;
        const int off = (((nt * 16 + l16) * 2) ^ ((row & 7) << 4));
        float v0 = fmaxf(acc0[nt][r] + bv[nt], 0.f);
        float v1 = fmaxf(acc1[nt][r] + bv[nt], 0.f);
        *(unsigned short*)(act0 + row * 512 + off) = f2bf(v0);
        *(unsigned short*)(act1 + row * 512 + off) = f2bf(v1);
      }
    }
    asm volatile("" ::: "memory");
  }

  // ---- layer 4: two N-128 halves h=0,1; q = h*5+kk (even->w4A, odd->w4B) --
#pragma unroll
  for (int h = 0; h < 2; ++h) {
    f32x4 a40[8], a41[8];
#pragma unroll
    for (int i = 0; i < 8; ++i) {
      a40[i] = f32x4{0.f, 0.f, 0.f, 0.f};
      a41[i] = f32x4{0.f, 0.f, 0.f, 0.f};
    }
#pragma unroll
    for (int kk = 0; kk < 5; ++kk) {
      const int q = h * 5 + kk;
      if (q < 9) {
        if (q & 1) { WISS8L4(w4A, q + 1); } else { WISS8L4(w4B, q + 1); }
      }
      bf16x8 af0 =
          *(const bf16x8*)(act0 + l16 * 512 + ((kk * 64 + lhalf * 16) ^ asw));
      bf16x8 af1 =
          *(const bf16x8*)(act1 + l16 * 512 + ((kk * 64 + lhalf * 16) ^ asw));
      __builtin_amdgcn_s_setprio(1);
#pragma unroll
      for (int i = 0; i < 8; ++i) {
        if (q & 1) {
          a40[i] = __builtin_amdgcn_mfma_f32_16x16x32_bf16(af0, w4B[i], a40[i],
                                                           0, 0, 0);
          a41[i] = __builtin_amdgcn_mfma_f32_16x16x32_bf16(af1, w4B[i], a41[i],
                                                           0, 0, 0);
        } else {
          a40[i] = __builtin_amdgcn_mfma_f32_16x16x32_bf16(af0, w4A[i], a40[i],
                                                           0, 0, 0);
          a41[i] = __builtin_amdgcn_mfma_f32_16x16x32_bf16(af1, w4A[i], a41[i],
                                                           0, 0, 0);
        }
      }
      __builtin_amdgcn_s_setprio(0);
    }
    // store this half for both groups
    float bv[8];
#pragma unroll
    for (int i = 0; i < 8; ++i) bv[i] = b3[(h * 8 + i) * 16 + l16];
    float* op0 = out + (size_t)(row0 + lhalf * 4) * 256 + h * 128 + l16;
    float* op1 = out + (size_t)(row0 + 16 + lhalf * 4) * 256 + h * 128 + l16;
#pragma unroll
    for (int i = 0; i < 8; ++i) {
#pragma unroll
      for (int r = 0; r < 4; ++r) {
        op0[(size_t)r * 256 + i * 16] = a40[i][r] + bv[i];
        op1[(size_t)r * 256 + i * 16] = a41[i][r] + bv[i];
      }
    }
  }
}

// ---------------- launcher ----------------
extern "C" void kernel_launch(void* const* d_in, const int* in_sizes, int n_in,
                              void* d_out, int out_size, void* d_ws, size_t ws_size,
                              hipStream_t stream) {
  const float* signal = (const float*)d_in[0];
  const float* comp   = (const float*)d_in[1];
  const float* Wm = (const float*)d_in[2];
  const float* bm = (const float*)d_in[3];
  const float* Wu = (const float*)d_in[4];
  const float* bu = (const float*)d_in[5];
  const float* W0 = (const float*)d_in[6];
  const float* b0 = (const float*)d_in[7];
  const float* W1 = (const float*)d_in[8];
  const float* b1 = (const float*)d_in[9];
  const float* W2 = (const float*)d_in[10];
  const float* b2 = (const float*)d_in[11];
  const float* W3 = (const float*)d_in[12];
  const float* b3 = (const float*)d_in[13];

  char* ws = (char*)d_ws;
  float* Wc    = (float*)(ws + 0);        // 33792 f32 (135168 B)
  float* bias1 = (float*)(ws + 135168);   // 160 f32
  float* b1p   = (float*)(ws + 135808);   // 160 f32
  float* b2p   = (float*)(ws + 136448);   // 160 f32
  // contiguous packed-weight sequence (chunk offsets off P1):
  unsigned short* P1 = (unsigned short*)(ws + 137216);  // 81920 u16 (160KB)
  unsigned short* P2 = (unsigned short*)(ws + 301056);  // 25600 u16 (50KB)
  unsigned short* P3 = (unsigned short*)(ws + 352256);  // 25600 u16 (50KB)
  unsigned short* P4 = (unsigned short*)(ws + 403456);  // 40960 u16 (80KB)
  unsigned short* csum = (unsigned short*)(ws + 485376); // [N,256] bf16 33.5MB

  hipLaunchKernelGGL(kA, dim3(2541), dim3(256), 0, stream,
                     comp, W0, Wu, Wm, bm, bu, b0, b1, b2, W1, W2, W3,
                     Wc, bias1, b1p, b2p, csum, P2, P3, P4);
  hipLaunchKernelGGL(kC, dim3(320), dim3(256), 0, stream, W0, Wc, P1);
  hipLaunchKernelGGL(kD, dim3(512), dim3(256), 65536, stream,
                     signal, csum, P1, bias1, b1p, b2p, b3, (float*)d_out);
}